// Round 3
// baseline (157.449 us; speedup 1.0000x reference)
//
#include <hip/hip_runtime.h>

// CGCoupler for METADATA=[128,128,128,128], max_l=3, overlap_out=True, trunc_in=True.
// Structure: T = K*128 (deg==128 for every valid block), indices are
// slot*128 + channel with slot in [0,16). Collapse to K unique (i1,i2,io,c)
// entries, CSR-sorted by io, then apply channelwise per batch row.

#define NCH        128
#define SLOTS_OUT  16
#define ROWS       2      // batch rows per block
#define BLOCK      128    // ROWS * NCH/2 threads (float2 per thread)
#define MAXK       512    // loose upper bound on unique entries (bound: ~296)
#define PREPB      256

// ---- prep: decode + counting-sort K unique entries by output slot ----
__global__ void prep_kernel(const float* __restrict__ cg,
                            const int* __restrict__ r1,
                            const int* __restrict__ r2,
                            const int* __restrict__ ro,
                            int K, int* __restrict__ segs,
                            int2* __restrict__ tab) {
    __shared__ int   sio[MAXK];
    __shared__ int   spack[MAXK];
    __shared__ float sc[MAXK];
    for (int k = threadIdx.x; k < K; k += PREPB) {
        const int t = k << 7;               // ns==0 element of each 128-run
        sio[k]   = ro[t] >> 7;              // output slot 0..15
        spack[k] = (r1[t] >> 7) | ((r2[t] >> 7) << 8);
        sc[k]    = cg[t];
    }
    __syncthreads();
    for (int k = threadIdx.x; k < K; k += PREPB) {
        const int myio = sio[k];
        int pos = 0;
        for (int j = 0; j < K; ++j) {
            const int jo = sio[j];
            pos += (int)((jo < myio) || (jo == myio && j < k));
        }
        tab[pos] = make_int2(spack[k], __float_as_int(sc[k]));
    }
    if (threadIdx.x <= SLOTS_OUT) {
        int cnt = 0;
        for (int j = 0; j < K; ++j) cnt += (int)(sio[j] < (int)threadIdx.x);
        segs[threadIdx.x] = cnt;            // segs[16] == K
    }
}

// ---- main: LDS-staged channelwise sparse bilinear coupling ----
__global__ __launch_bounds__(BLOCK) void couple_kernel(
        const float* __restrict__ x1, const float* __restrict__ x2,
        const int* __restrict__ segs_g, const int2* __restrict__ tab_g,
        float* __restrict__ out) {
    __shared__ float xs[2][ROWS * 2048];    // 32 KB: [x1|x2][row][slot*128+ch]
    __shared__ int2  tab[MAXK];
    __shared__ int   segs[SLOTS_OUT + 1];
    __shared__ int   Ksh;

    const int tid = threadIdx.x;
    const long long rowbase = (long long)blockIdx.x * (ROWS * 2048);

    // stage two rows of x1 and x2, coalesced float4
    const float4* g1 = (const float4*)(x1 + rowbase);
    const float4* g2 = (const float4*)(x2 + rowbase);
    float4* s1 = (float4*)&xs[0][0];
    float4* s2 = (float4*)&xs[1][0];
    #pragma unroll
    for (int i = 0; i < (ROWS * 2048 / 4) / BLOCK; ++i) {
        s1[tid + i * BLOCK] = g1[tid + i * BLOCK];
        s2[tid + i * BLOCK] = g2[tid + i * BLOCK];
    }
    if (tid == 0) Ksh = segs_g[SLOTS_OUT];
    if (tid <= SLOTS_OUT) segs[tid] = segs_g[tid];
    __syncthreads();
    for (int i = tid; i < Ksh; i += BLOCK) tab[i] = tab_g[i];
    __syncthreads();

    const int row   = tid >> 6;             // 0..ROWS-1
    const int choff = (tid & 63) << 1;      // even channel 0..126
    const int xbase = (row << 11) + choff;  // row*2048 + choff

    float* orow = out + rowbase + (long long)row * 2048 + choff;

    #pragma unroll
    for (int io = 0; io < SLOTS_OUT; ++io) {
        float ax = 0.f, ay = 0.f;
        const int kend = segs[io + 1];
        for (int k = segs[io]; k < kend; ++k) {
            const int2 e = tab[k];
            const float c = __int_as_float(e.y);
            const float2 a = *(const float2*)&xs[0][xbase + ((e.x & 0xff) << 7)];
            const float2 b = *(const float2*)&xs[1][xbase + (((e.x >> 8) & 0xff) << 7)];
            ax += c * a.x * b.x;
            ay += c * a.y * b.y;
        }
        *(float2*)&orow[io << 7] = make_float2(ax, ay);
    }
}

extern "C" void kernel_launch(void* const* d_in, const int* in_sizes, int n_in,
                              void* d_out, int out_size, void* d_ws, size_t ws_size,
                              hipStream_t stream) {
    const float* x1 = (const float*)d_in[0];
    const float* x2 = (const float*)d_in[1];
    const float* cg = (const float*)d_in[2];
    const int*   r1 = (const int*)d_in[3];
    const int*   r2 = (const int*)d_in[4];
    const int*   ro = (const int*)d_in[5];
    float* out = (float*)d_out;

    const int T = in_sizes[2];
    const int K = T >> 7;                   // unique entries (~150, <=MAXK)
    const int B = in_sizes[0] / 2048;       // 4096

    int*  segs = (int*)d_ws;                // 17 ints
    int2* tab  = (int2*)((char*)d_ws + 128);// K entries, 8B each

    prep_kernel<<<1, PREPB, 0, stream>>>(cg, r1, r2, ro, K, segs, tab);
    couple_kernel<<<B / ROWS, BLOCK, 0, stream>>>(x1, x2, segs, tab, out);
}

// Round 5
// 146.054 us; speedup vs baseline: 1.0780x; 1.0780x over previous
//
#include <hip/hip_runtime.h>

// CGCoupler for METADATA=[128,128,128,128], max_l=3, overlap_out=True, trunc_in=True.
// T = K*128 (deg==128 everywhere), indices are slot*128+channel, slot in [0,16).
// Prep collapses to K unique (i1,i2,io,c) entries and scatters them into a DENSE
// padded table [16 io][PAD] (zero-coeff padding; desk-checked per-slot max <= 12).
// Main kernel is fully static: 16x16 unrolled FMA stream, uniform table loads,
// independent LDS gathers -> no dependent-latency chains (round-3 bottleneck).

#define SLOTS_OUT  16
#define PAD        16     // max entries per output slot (enumerated max: 12)
#define ROWS       2      // batch rows per block
#define BLOCK      128    // ROWS * 64 threads, float2 (2 channels) per thread
#define MAXK       512
#define PREPB      256

// ---- prep: decode K unique entries, scatter into dense padded [16][PAD] table ----
__global__ void prep_kernel(const float* __restrict__ cg,
                            const int* __restrict__ r1,
                            const int* __restrict__ r2,
                            const int* __restrict__ ro,
                            int K, int2* __restrict__ ptab) {
    __shared__ int   sio[MAXK];
    __shared__ int   spack[MAXK];
    __shared__ float sc[MAXK];
    // zero-init padded table (coeff 0, slots 0 -> harmless reads, no contribution)
    for (int i = threadIdx.x; i < SLOTS_OUT * PAD; i += PREPB)
        ptab[i] = make_int2(0, 0);
    for (int k = threadIdx.x; k < K; k += PREPB) {
        const int t = k << 7;               // ns==0 element of each 128-run
        sio[k]   = ro[t] >> 7;              // output slot 0..15
        spack[k] = (r1[t] >> 7) | ((r2[t] >> 7) << 8);
        sc[k]    = cg[t];
    }
    __syncthreads();
    if (threadIdx.x < SLOTS_OUT) {          // one thread per io slot, keep input order
        const int io = threadIdx.x;
        int cnt = 0;
        for (int j = 0; j < K; ++j) {
            if (sio[j] == io && cnt < PAD) {
                ptab[io * PAD + cnt] = make_int2(spack[j], __float_as_int(sc[j]));
                ++cnt;
            }
        }
    }
}

// ---- main: LDS-staged, fully-static channelwise sparse bilinear coupling ----
__global__ __launch_bounds__(BLOCK, 2) void couple_kernel(
        const float* __restrict__ x1, const float* __restrict__ x2,
        const int2* __restrict__ tab_g, float* __restrict__ out) {
    __shared__ float xs[2][ROWS * 2048];    // 32 KB: [x1|x2][row][slot*128+ch]

    const int tid = threadIdx.x;
    const long long rowbase = (long long)blockIdx.x * (ROWS * 2048);

    // stage two rows of x1 and x2, coalesced float4 (reg-staged; known-good)
    const float4* g1 = (const float4*)(x1 + rowbase);
    const float4* g2 = (const float4*)(x2 + rowbase);
    float4* s1 = (float4*)&xs[0][0];
    float4* s2 = (float4*)&xs[1][0];
    #pragma unroll
    for (int i = 0; i < (ROWS * 2048 / 4) / BLOCK; ++i) {
        s1[tid + i * BLOCK] = g1[tid + i * BLOCK];
        s2[tid + i * BLOCK] = g2[tid + i * BLOCK];
    }
    __syncthreads();

    const int row   = tid >> 6;             // 0..ROWS-1
    const int choff = (tid & 63) << 1;      // even channel 0..126
    const float* xa = &xs[0][(row << 11) + choff];
    const float* xb = &xs[1][(row << 11) + choff];
    float* orow = out + rowbase + (long long)row * 2048 + choff;

    #pragma unroll
    for (int io = 0; io < SLOTS_OUT; ++io) {
        float ax = 0.f, ay = 0.f;
        #pragma unroll
        for (int j = 0; j < PAD; ++j) {
            // compile-time index -> uniform (scalarizable, batchable) load
            const int2 e = tab_g[io * PAD + j];
            const float c = __int_as_float(e.y);
            const float2 a = *(const float2*)(xa + ((e.x & 0xff) << 7));
            const float2 b = *(const float2*)(xb + ((e.x >> 8) << 7));
            ax = fmaf(c * a.x, b.x, ax);
            ay = fmaf(c * a.y, b.y, ay);
        }
        *(float2*)&orow[io << 7] = make_float2(ax, ay);
    }
}

extern "C" void kernel_launch(void* const* d_in, const int* in_sizes, int n_in,
                              void* d_out, int out_size, void* d_ws, size_t ws_size,
                              hipStream_t stream) {
    const float* x1 = (const float*)d_in[0];
    const float* x2 = (const float*)d_in[1];
    const float* cg = (const float*)d_in[2];
    const int*   r1 = (const int*)d_in[3];
    const int*   r2 = (const int*)d_in[4];
    const int*   ro = (const int*)d_in[5];
    float* out = (float*)d_out;

    const int T = in_sizes[2];
    const int K = T >> 7;                   // unique entries (~150)
    const int B = in_sizes[0] / 2048;       // 4096

    int2* ptab = (int2*)d_ws;               // 256 int2 = 2 KB

    prep_kernel<<<1, PREPB, 0, stream>>>(cg, r1, r2, ro, K, ptab);
    couple_kernel<<<B / ROWS, BLOCK, 0, stream>>>(x1, x2, ptab, out);
}

// Round 8
// 115.415 us; speedup vs baseline: 1.3642x; 1.2655x over previous
//
#include <hip/hip_runtime.h>
#include <utility>

// CGCoupler METADATA=[128,128,128,128], max_l=3, parity=0, overlap_out=True,
// trunc_in=True. Indices collapse to slot*128+channel (slot in [0,16), 16 = sum
// of 2l+1 for l=0..3). The SPARSITY STRUCTURE is compile-time: real-CG entry
// (l1,m1),(l2,m2)->(lout,mo) can be nonzero only if |mo| in {|m1|+|m2|,||m1|-|m2||}
// (complex->real basis couples only equal |m|; complex CG needs c=a+b), over
// triples with l1+l2<=3 (trunc_in), |l1-l2|<=lout<=l1+l2. Superset: 284 entries,
// 70 distinct (i1,i2) pairs; actual nonzeros ~150, rest get coeff 0 from prep.
// Main kernel: no LDS, 32 independent coalesced float2 loads -> registers,
// template-emitted static FMA stream (shared a*b products), 16 float2 stores.

#define NSLOT 16

struct Ent { unsigned char i1, i2, io, pad; };

struct Tab {
    Ent ent[320];               // grouped by (i1,i2) pair
    unsigned char p1[80], p2[80];
    short ps[81];               // pair segment starts into ent[]
    int npair, nent;
};

constexpr int slotof(int l, int m) { return l * l + m + l; }

constexpr bool triple_ok(int lo, int l1, int l2) {
    if (l1 + l2 > 3) return false;          // trunc_in, max_l=3
    if (l1 + l2 < lo) return false;
    int d = l1 - l2; if (d < 0) d = -d;
    return d <= lo;
}

constexpr Tab build_tab() {
    Tab t{};
    Ent raw[512]{}; int n = 0;
    for (int lo = 0; lo <= 3; ++lo)
        for (int l1 = 0; l1 <= 3; ++l1)
            for (int l2 = 0; l2 <= 3; ++l2) {
                if (!triple_ok(lo, l1, l2)) continue;
                for (int m1 = -l1; m1 <= l1; ++m1)
                    for (int m2 = -l2; m2 <= l2; ++m2)
                        for (int mo = -lo; mo <= lo; ++mo) {
                            int a1 = m1 < 0 ? -m1 : m1, a2 = m2 < 0 ? -m2 : m2;
                            int ao = mo < 0 ? -mo : mo;
                            int s = a1 + a2, d = a1 - a2; if (d < 0) d = -d;
                            if (ao != s && ao != d) continue;
                            raw[n].i1 = (unsigned char)slotof(l1, m1);
                            raw[n].i2 = (unsigned char)slotof(l2, m2);
                            raw[n].io = (unsigned char)slotof(lo, mo);
                            ++n;
                        }
            }
    int np = 0, ne = 0;
    for (int a = 0; a < NSLOT; ++a)
        for (int b = 0; b < NSLOT; ++b) {
            int cnt = 0;
            for (int k = 0; k < n; ++k)
                if (raw[k].i1 == a && raw[k].i2 == b) { t.ent[ne++] = raw[k]; ++cnt; }
            if (cnt) {
                t.p1[np] = (unsigned char)a; t.p2[np] = (unsigned char)b;
                t.ps[np] = (short)(ne - cnt); ++np;
            }
        }
    t.ps[np] = (short)ne; t.npair = np; t.nent = ne;
    return t;
}

__device__ constexpr Tab TT = build_tab();
constexpr int NENT  = build_tab().nent;
constexpr int NPAIR = build_tab().npair;
static_assert(NENT <= 320 && NPAIR <= 80, "table overflow");

// ---- prep: scatter actual coefficients into compact entry-order array ----
__global__ void prep_kernel(const float* __restrict__ cg,
                            const int* __restrict__ r1,
                            const int* __restrict__ r2,
                            const int* __restrict__ ro,
                            int K, float* __restrict__ cc) {
    __shared__ float dense[NSLOT * NSLOT * NSLOT];   // [i1][i2][io], 16 KB
    for (int i = threadIdx.x; i < NSLOT * NSLOT * NSLOT; i += 256) dense[i] = 0.f;
    __syncthreads();
    for (int k = threadIdx.x; k < K; k += 256) {
        const int t = k << 7;                        // ns==0 of each 128-run
        const int key = ((r1[t] >> 7) << 8) | ((r2[t] >> 7) << 4) | (ro[t] >> 7);
        dense[key] = cg[t];
    }
    __syncthreads();
    for (int j = threadIdx.x; j < NENT; j += 256) {
        const Ent e = TT.ent[j];
        cc[j] = dense[((int)e.i1 << 8) | ((int)e.i2 << 4) | (int)e.io];
    }
}

// ---- static FMA stream emission (all indices template-constant) ----
template<int J>
__device__ __forceinline__ void fma_ent(const float* __restrict__ cc,
                                        const float2 p, float2* acc) {
    constexpr int io = TT.ent[J].io;
    const float c = cc[J];
    acc[io].x = fmaf(c, p.x, acc[io].x);
    acc[io].y = fmaf(c, p.y, acc[io].y);
}

template<int P, int... Js>
__device__ __forceinline__ void pair_body(const float2* a, const float2* b,
                                          const float* __restrict__ cc, float2* acc,
                                          std::integer_sequence<int, Js...>) {
    constexpr int i1 = TT.p1[P], i2 = TT.p2[P], s0 = TT.ps[P];
    const float2 p = make_float2(a[i1].x * b[i2].x, a[i1].y * b[i2].y);
    (fma_ent<s0 + Js>(cc, p, acc), ...);
}

template<int... Ps>
__device__ __forceinline__ void all_pairs(const float2* a, const float2* b,
                                          const float* __restrict__ cc, float2* acc,
                                          std::integer_sequence<int, Ps...>) {
    (pair_body<Ps>(a, b, cc, acc,
         std::make_integer_sequence<int, (int)(TT.ps[Ps + 1] - TT.ps[Ps])>{}), ...);
}

// ---- main: register-resident channelwise sparse bilinear coupling ----
__global__ __launch_bounds__(256) void couple_kernel(
        const float* __restrict__ x1, const float* __restrict__ x2,
        const float* __restrict__ cc, float* __restrict__ out) {
    const int tid = threadIdx.x;
    const int row = (blockIdx.x << 2) + (tid >> 6);  // 4 rows per block
    const int ch  = (tid & 63) << 1;                 // even channel 0..126
    const long long base = (long long)row * 2048 + ch;

    float2 a[NSLOT], b[NSLOT];
    #pragma unroll
    for (int s = 0; s < NSLOT; ++s) {
        a[s] = *(const float2*)(x1 + base + (s << 7));
        b[s] = *(const float2*)(x2 + base + (s << 7));
    }
    float2 acc[NSLOT];
    #pragma unroll
    for (int s = 0; s < NSLOT; ++s) acc[s] = make_float2(0.f, 0.f);

    all_pairs(a, b, cc, acc, std::make_integer_sequence<int, NPAIR>{});

    #pragma unroll
    for (int s = 0; s < NSLOT; ++s)
        *(float2*)(out + base + (s << 7)) = acc[s];
}

extern "C" void kernel_launch(void* const* d_in, const int* in_sizes, int n_in,
                              void* d_out, int out_size, void* d_ws, size_t ws_size,
                              hipStream_t stream) {
    const float* x1 = (const float*)d_in[0];
    const float* x2 = (const float*)d_in[1];
    const float* cg = (const float*)d_in[2];
    const int*   r1 = (const int*)d_in[3];
    const int*   r2 = (const int*)d_in[4];
    const int*   ro = (const int*)d_in[5];
    float* out = (float*)d_out;

    const int T = in_sizes[2];
    const int K = T >> 7;                   // actual unique entries (~150)
    const int B = in_sizes[0] / 2048;       // 4096 rows

    float* cc = (float*)d_ws;               // NENT floats (~1.2 KB)

    prep_kernel<<<1, 256, 0, stream>>>(cg, r1, r2, ro, K, cc);
    couple_kernel<<<B / 4, 256, 0, stream>>>(x1, x2, cc, out);
}